// Round 3
// baseline (25436.742 us; speedup 1.0000x reference)
//
#include <hip/hip_runtime.h>
#include <stdint.h>

#define Bsz 64
#define Tsz 1024
#define NIc 128
#define NHc 512
#define DTc 0.1f

typedef __attribute__((ext_vector_type(8))) short short8;
typedef __attribute__((ext_vector_type(4))) float f32x4;

static __device__ __forceinline__ unsigned short f2bf(float f) {
  union { float f; uint32_t u; } v; v.f = f;
  return (unsigned short)((v.u + 0x7fffu + ((v.u >> 16) & 1u)) >> 16);
}
static __device__ __forceinline__ float bf2f(unsigned short h) {
  union { float f; uint32_t u; } v; v.u = ((uint32_t)h) << 16; return v.f;
}
static __device__ __forceinline__ float fast_tanh(float xx) {
  float a = __builtin_fabsf(xx);
  float e = __expf(-2.0f * a);
  float r = (1.0f - e) / (1.0f + e);
  return __builtin_copysignf(r, xx);
}

// ---------- kernel 0: pack h2h into bf16 MFMA B-frag layouts ----------
// wb1[nt][kb][lane][e] = h2h[kb*32+quad*8+e][nt*16+l15]   (B for hy@W)
// wb2[nt][kb][lane][e] = h2h[nt*16+l15][kb*32+quad*8+e]   (B for pre@W^T)
__global__ __launch_bounds__(256, 1)
void pirn_prep(const float* __restrict__ h2h, unsigned short* __restrict__ wb)
{
  int idx  = blockIdx.x * 256 + threadIdx.x;   // 32*16*64 = 32768 total
  int lane = idx & 63;
  int kb   = (idx >> 6) & 15;
  int nt   = idx >> 10;
  int l15  = lane & 15, quad = lane >> 4;
  int n  = nt * 16 + l15;
  int k0 = kb * 32 + quad * 8;
  short8 v1, v2;
#pragma unroll
  for (int e = 0; e < 8; ++e) {
    v1[e] = (short)f2bf(h2h[(size_t)(k0 + e) * NHc + n]);
    v2[e] = (short)f2bf(h2h[(size_t)n * NHc + k0 + e]);
  }
  size_t off = ((size_t)(nt * 16 + kb) * 64 + lane) * 8;
  *(short8*)(wb + off) = v1;
  *(short8*)(wb + (size_t)NHc * NHc + off) = v2;
}

// ---------- kernel 1: forcing = tanh(x @ x2h), 256 WGs ----------
__global__ __launch_bounds__(256, 1)
void pirn_force(const float* __restrict__ x, const float* __restrict__ x2h,
                float* __restrict__ out)
{
  __shared__ __align__(16) char lds[34816];
  const int tid  = threadIdx.x;
  const int lane = tid & 63;
  const int wv   = tid >> 6;
  const int l15  = lane & 15;
  const int quad = lane >> 4;
  unsigned short* x2ht_hi = (unsigned short*)lds;             // [64][136]
  unsigned short* x2ht_lo = (unsigned short*)(lds + 17408);   // [64][136]
  const long R0 = (long)blockIdx.x * 256;

  for (int pass = 0; pass < 8; ++pass) {
    const int c0 = pass * 64;
    __syncthreads();
    for (int i = tid; i < 64 * NIc; i += 256) {
      int c = i & 63; int k = i >> 6;
      float v = x2h[k * NHc + c0 + c];
      unsigned short hi = f2bf(v);
      x2ht_hi[c * 136 + k] = hi;
      x2ht_lo[c * 136 + k] = f2bf(v - bf2f(hi));
    }
    __syncthreads();
    for (int mt = wv * 4; mt < wv * 4 + 4; ++mt) {
      const float* xr = x + (R0 + mt * 16 + l15) * NIc;
      short8 ahi[4], alo[4];
#pragma unroll
      for (int kb = 0; kb < 4; ++kb) {
        int k0 = kb * 32 + quad * 8;
        f32x4 v0 = *(const f32x4*)(xr + k0);
        f32x4 v1 = *(const f32x4*)(xr + k0 + 4);
#pragma unroll
        for (int e = 0; e < 4; ++e) {
          unsigned short h0 = f2bf(v0[e]);
          ahi[kb][e] = (short)h0;
          alo[kb][e] = (short)f2bf(v0[e] - bf2f(h0));
          unsigned short h1 = f2bf(v1[e]);
          ahi[kb][e + 4] = (short)h1;
          alo[kb][e + 4] = (short)f2bf(v1[e] - bf2f(h1));
        }
      }
#pragma unroll
      for (int nt = 0; nt < 4; ++nt) {
        f32x4 acc0 = {0.f, 0.f, 0.f, 0.f};
        f32x4 acc1 = {0.f, 0.f, 0.f, 0.f};
#pragma unroll
        for (int kb = 0; kb < 4; ++kb) {
          int k0 = kb * 32 + quad * 8;
          short8 bhi = *(const short8*)(x2ht_hi + (nt * 16 + l15) * 136 + k0);
          short8 blo = *(const short8*)(x2ht_lo + (nt * 16 + l15) * 136 + k0);
          acc0 = __builtin_amdgcn_mfma_f32_16x16x32_bf16(ahi[kb], bhi, acc0, 0, 0, 0);
          acc1 = __builtin_amdgcn_mfma_f32_16x16x32_bf16(alo[kb], bhi, acc1, 0, 0, 0);
          acc0 = __builtin_amdgcn_mfma_f32_16x16x32_bf16(ahi[kb], blo, acc0, 0, 0, 0);
        }
        long orow = R0 + mt * 16 + quad * 4;
        int oc = c0 + nt * 16 + l15;
#pragma unroll
        for (int r = 0; r < 4; ++r)
          out[(orow + r) * NHc + oc] = fast_tanh(acc0[r] + acc1[r]);
      }
    }
  }
}

// ---------- kernel 2: zero-sync recurrent scan, 4 WGs x 16 batch rows ----------
__global__ __launch_bounds__(256, 1)
void pirn_recur(const float* __restrict__ bias, const float* __restrict__ gam_p,
                const float* __restrict__ eps_p,
                const unsigned short* __restrict__ wb,
                float* __restrict__ out)
{
  __shared__ __align__(16) unsigned short preL[16 * 520];
  __shared__ __align__(16) unsigned short hyL[16 * 520];
  const int g    = blockIdx.x;          // batch rows g*16 .. g*16+15
  const int tid  = threadIdx.x;
  const int lane = tid & 63;
  const int w    = tid >> 6;            // wave: owns n-tiles w*8 .. w*8+7
  const int l15  = lane & 15;
  const int quad = lane >> 4;

  const unsigned short* wb1 = wb;                          // [32][16][64][8]
  const unsigned short* wb2 = wb + (size_t)NHc * NHc;

  float b8[8], g8[8], e8[8];
#pragma unroll
  for (int i = 0; i < 8; ++i) {
    int col = (w * 8 + i) * 16 + l15;
    b8[i] = bias[col]; g8[i] = gam_p[col]; e8[i] = eps_p[col];
  }

  short8 hyA[16];
#pragma unroll
  for (int kb = 0; kb < 16; ++kb) hyA[kb] = (short8)0;
  f32x4 hyf[8], hzf[8];
#pragma unroll
  for (int i = 0; i < 8; ++i) { hyf[i] = (f32x4)0.f; hzf[i] = (f32x4)0.f; }

  const int  row0 = g * 16 + quad * 4;                    // global batch row base (C rows)
  const unsigned short* wv1 = wb1 + (size_t)w * 65536;    // wave's n-tile slab
  const unsigned short* wv2 = wb2 + (size_t)w * 65536;

  for (int t = 0; t < Tsz; ++t) {
    // forcing u (written by pirn_force; read-before-overwrite within this thread)
    float u[8][4];
#pragma unroll
    for (int i = 0; i < 8; ++i)
#pragma unroll
      for (int r = 0; r < 4; ++r)
        u[i][r] = out[((size_t)(row0 + r) * Tsz + t) * NHc + (w * 8 + i) * 16 + l15];

    // ---- phase 1: pre = tanh(hy @ W + b) ----
    f32x4 acc[8];
#pragma unroll
    for (int i = 0; i < 8; ++i) acc[i] = (f32x4)0.f;
#pragma unroll
    for (int kb = 0; kb < 16; ++kb) {
#pragma unroll
      for (int i = 0; i < 8; ++i) {
        short8 b = *(const short8*)(wv1 + ((size_t)(i * 16 + kb) * 64 + lane) * 8);
        acc[i] = __builtin_amdgcn_mfma_f32_16x16x32_bf16(hyA[kb], b, acc[i], 0, 0, 0);
      }
    }
#pragma unroll
    for (int i = 0; i < 8; ++i) {
#pragma unroll
      for (int r = 0; r < 4; ++r) {
        float p = fast_tanh(acc[i][r] + b8[i]);
        preL[(quad * 4 + r) * 520 + (w * 8 + i) * 16 + l15] = f2bf(p);
      }
    }
    __syncthreads();
    short8 pA[16];
#pragma unroll
    for (int kb = 0; kb < 16; ++kb)
      pA[kb] = *(const short8*)(preL + l15 * 520 + kb * 32 + quad * 8);

    // ---- phase 2: c2 = pre @ W^T ----
    f32x4 ac2[8];
#pragma unroll
    for (int i = 0; i < 8; ++i) ac2[i] = (f32x4)0.f;
#pragma unroll
    for (int kb = 0; kb < 16; ++kb) {
#pragma unroll
      for (int i = 0; i < 8; ++i) {
        short8 b = *(const short8*)(wv2 + ((size_t)(i * 16 + kb) * 64 + lane) * 8);
        ac2[i] = __builtin_amdgcn_mfma_f32_16x16x32_bf16(pA[kb], b, ac2[i], 0, 0, 0);
      }
    }

    // ---- state update + output + hy->LDS for next step's A-frags ----
#pragma unroll
    for (int i = 0; i < 8; ++i) {
#pragma unroll
      for (int r = 0; r < 4; ++r) {
        float hz = hzf[i][r] + DTc * (u[i][r] - ac2[i][r] - g8[i] * hyf[i][r] - e8[i] * hzf[i][r]);
        hzf[i][r] = hz;
        hyf[i][r] += DTc * hz;
        out[((size_t)(row0 + r) * Tsz + t) * NHc + (w * 8 + i) * 16 + l15] = hyf[i][r];
        hyL[(quad * 4 + r) * 520 + (w * 8 + i) * 16 + l15] = f2bf(hyf[i][r]);
      }
    }
    __syncthreads();
#pragma unroll
    for (int kb = 0; kb < 16; ++kb)
      hyA[kb] = *(const short8*)(hyL + l15 * 520 + kb * 32 + quad * 8);
  }

  // final hy tail
#pragma unroll
  for (int i = 0; i < 8; ++i)
#pragma unroll
    for (int r = 0; r < 4; ++r)
      out[(size_t)Bsz * Tsz * NHc + (size_t)(row0 + r) * NHc + (w * 8 + i) * 16 + l15] = hyf[i][r];
}

extern "C" void kernel_launch(void* const* d_in, const int* in_sizes, int n_in,
                              void* d_out, int out_size, void* d_ws, size_t ws_size,
                              hipStream_t stream) {
  const float* x    = (const float*)d_in[0];
  const float* x2h  = (const float*)d_in[1];
  const float* h2h  = (const float*)d_in[2];
  const float* bias = (const float*)d_in[3];
  const float* gam  = (const float*)d_in[4];
  const float* eps  = (const float*)d_in[5];
  (void)in_sizes; (void)n_in; (void)out_size; (void)ws_size;
  pirn_prep<<<dim3(128), dim3(256), 0, stream>>>(h2h, (unsigned short*)d_ws);
  pirn_force<<<dim3(256), dim3(256), 0, stream>>>(x, x2h, (float*)d_out);
  pirn_recur<<<dim3(4), dim3(256), 0, stream>>>(bias, gam, eps,
                                                (const unsigned short*)d_ws,
                                                (float*)d_out);
}